// Round 7
// baseline (225.521 us; speedup 1.0000x reference)
//
#include <hip/hip_runtime.h>

// Problem constants
#define LSEQ   16384
#define NB     20
#define NBATCH 128
#define TAPS   513
#define CT     (2*TAPS - 1)   // 1025 combined (autocorrelation) taps
#define MAXSTEP 80            // k-step table rows per band (Npad+3 <= 75 fits)

// Main-kernel tiling
#define TT     2048           // output times per block
#define SPANE  3088           // staged ext ushorts per batch row (max read = 3072)
#define STRIDE 3096           // row stride in ushorts (16B-aligned)
#define EXTEND 16896          // 512 + LSEQ
#define GMAX   17407          // last valid ext index (LSEQ + 2*512 - 1)

// ws layout (bytes)
#define HDR_OFF  0            // int2 per band {k0, nsteps}: 160 B
#define CS_OFF   4096         // fp32 autocorr: 20 * CSTRIDE floats = 83.2 KB
#define CSTRIDE  1040         // floats per band row (1025 padded)
#define ATAB_OFF 98304        // bf16 A-fragment table: 20*80*64*16 B = 1.64 MB

typedef short  v8s  __attribute__((ext_vector_type(8)));
typedef __bf16 v8bf __attribute__((ext_vector_type(8)));
typedef float  v16f __attribute__((ext_vector_type(16)));

__device__ __forceinline__ unsigned short f2bf(float f) {  // RNE fp32->bf16
    union { float f; unsigned u; } v; v.f = f;
    return (unsigned short)((v.u + 0x7fffu + ((v.u >> 16) & 1u)) >> 16);
}

__device__ __forceinline__ v16f vzero() {
    v16f z;
    #pragma unroll
    for (int i = 0; i < 16; ++i) z[i] = 0.f;
    return z;
}

// 16B-granular XOR swizzle on LDS dword addresses: spreads the 4 tb lanes
// (64-dword stride, bits [7:6]) across 4 chunk slots (bits [3:2]) so the
// window ds_read_b128 is ~2-way (free) instead of 8-way. Involution; applied
// identically at staging-write and fragment-read.
__device__ __forceinline__ v8bf ld_swz(const unsigned short* base, int ldw) {
    int ph = ldw ^ (((ldw >> 6) & 3) << 2);
    return __builtin_bit_cast(v8bf, *(const v8s*)((const char*)base + (size_t)ph * 4));
}

// ---- Autocorr kernel: grid (20 bands, 9 chunks of 128 d) x 512 threads ----
__global__ __launch_bounds__(512) void autoc_kernel(
    const float* __restrict__ Kg, float* __restrict__ Cs)
{
    __shared__ __align__(16) float kk4[4][520];
    __shared__ float ps[512];
    const int band = blockIdx.x, y = blockIdx.y;
    const int tid = threadIdx.x;
    const int rel = tid & 127, q = tid >> 7;
    const int d = 128 * y + rel;

    for (int j = tid; j < TAPS; j += 512) {
        float v = Kg[band * TAPS + j];
        kk4[0][j] = v;
        if (j >= 1) kk4[1][j - 1] = v;
        if (j >= 2) kk4[2][j - 2] = v;
        if (j >= 3) kk4[3][j - 3] = v;
    }
    if (tid < 40) {   // zero shifted-copy tails [TAPS-c, 520)
        int c = tid / 10, t = tid % 10;
        int j = 510 + t;
        if (j >= TAPS - c && j < 520) kk4[c][j] = 0.f;
    }
    __syncthreads();

    float s = 0.f;
    if (d < CT) {
        int al = d - 512; if (al < 0) al = -al;
        const int n  = TAPS - al;
        const int c  = al & 3, sh4 = (al >> 2) << 2;
        const int nq = (((n + 3) >> 2) + 3) & ~3;
        int i0 = q * nq, i1 = i0 + nq; if (i1 > n) i1 = n;
        float s0 = 0.f, s1 = 0.f, s2 = 0.f, s3 = 0.f;
        int i = i0;
        for (; i + 3 < i1; i += 4) {
            float4 a = *(const float4*)&kk4[0][i];
            float4 b = *(const float4*)&kk4[c][i + sh4];
            s0 = fmaf(a.x, b.x, s0);
            s1 = fmaf(a.y, b.y, s1);
            s2 = fmaf(a.z, b.z, s2);
            s3 = fmaf(a.w, b.w, s3);
        }
        for (; i < i1; ++i) s0 = fmaf(kk4[0][i], kk4[c][i + sh4], s0);
        s = (s0 + s1) + (s2 + s3);
    }
    ps[tid] = s;
    __syncthreads();
    if (q == 0 && d < CT) {
        float tot = (ps[rel] + ps[rel + 128]) + (ps[rel + 256] + ps[rel + 384]);
        Cs[band * CSTRIDE + d] = tot;
    }
}

// ---- Table kernel: one block per band; stage C in LDS, range-scan, emit ----
__global__ __launch_bounds__(1024) void table_kernel(
    const float* __restrict__ Cs, int2* __restrict__ hdr, short* __restrict__ atab)
{
    __shared__ float csh[CT];
    __shared__ int smin, smax, sk0, sN;
    const int band = blockIdx.x, tid = threadIdx.x;
    if (tid == 0) { smin = CT; smax = 0; }
    __syncthreads();

    const float* cb = Cs + band * CSTRIDE;
    int lmin = CT, lmax = 0;
    for (int j = tid; j < CT; j += 1024) {
        float v = cb[j];
        csh[j] = v;
        if (v != 0.f) { if (j < lmin) lmin = j; if (j > lmax) lmax = j; }
    }
    if (lmin < CT) atomicMin(&smin, lmin);
    if (lmax > 0)  atomicMax(&smax, lmax);
    __syncthreads();

    if (tid == 0) {
        int k0 = smin & ~15;
        int k1 = ((smax + 31) >> 4) << 4;
        int N  = (k1 - k0) / 16 + 1;              // <= 66
        int2 h; h.x = k0; h.y = N;
        hdr[band] = h;
        sk0 = k0; sN = N;
    }
    __syncthreads();

    const int k0 = sk0, N = sN;
    const int Np = (N + 7) & ~7;                  // main kernel pads to x8
    int nf = Np + 3; if (nf > MAXSTEP) nf = MAXSTEP;
    for (int idx = tid; idx < nf * 64; idx += 1024) {
        int s = idx >> 6, lane = idx & 63;
        int m = lane & 31, kh = lane >> 5;
        int base = k0 + 16 * s + 8 * kh - m;
        v8s r;
        #pragma unroll
        for (int j = 0; j < 8; ++j) {
            int ci = base + j;
            float v = (ci >= 0 && ci < CT) ? csh[ci] : 0.f;  // rows >= N are all-zero
            r[j] = (short)f2bf(v);
        }
        *(v8s*)(atab + ((size_t)(band * MAXSTEP + s) * 64 + lane) * 8) = r;
    }
}

// ---- Main kernel: stage ext once, sweep a band group, MFMA 32x32x16 ----
// Block: 8 batches x 2048 times, 4 waves (wave w: times [512w, 512w+512)).
// Wave tile: m = fine time (32), n = brow + 8*tb (8 batches x 4 time-subtiles
// of 128); 4 accumulators at time offsets 0/32/64/96. With k-step 16, acc_j
// at step s needs the B fragment at u = s + 2j of ONE sliding stream ->
// rolling 8-fragment register window: 1 ds_read_b128 + 4 MFMA per step
// (was 4 reads + 4 MFMA). Window depth 7 also hides all LDS latency.
__global__ __launch_bounds__(256, 3) void filt_main(
    const float* __restrict__ x, const short* __restrict__ atab,
    const int2* __restrict__ hdr, float* __restrict__ out)
{
    __shared__ __align__(16) unsigned short extl[8 * STRIDE];
    const int tid = threadIdx.x;
    const int tile = blockIdx.x, grp = blockIdx.y, bg = blockIdx.z;
    const int T0 = tile * TT;

    // ---- Stage odd-extended x as bf16 (8 batch rows, swizzled writes) ----
    const bool edge = (T0 < 512) || (T0 + SPANE > EXTEND);
    for (int b = 0; b < 8; ++b) {
        const float* xb = x + (size_t)(bg * 8 + b) * LSEQ;
        float x0 = 0.f, xN = 0.f;
        if (edge) { x0 = xb[0]; xN = xb[LSEQ - 1]; }
        for (int e4 = tid; e4 < SPANE / 4; e4 += 256) {
            const int e = 4 * e4;
            const int g0 = T0 + e;
            float v0, v1, v2, v3;
            if (g0 >= 512 && g0 + 4 <= EXTEND) {
                float4 xv = *(const float4*)(xb + (g0 - 512));
                v0 = xv.x; v1 = xv.y; v2 = xv.z; v3 = xv.w;
            } else {
                float vv[4];
                #pragma unroll
                for (int t = 0; t < 4; ++t) {
                    int g = g0 + t; if (g > GMAX) g = GMAX;
                    vv[t] = (g < 512)    ? 2.f * x0 - xb[512 - g]
                          : (g < EXTEND) ? xb[g - 512]
                          :                2.f * xN - xb[2 * LSEQ + 512 - 2 - g];
                }
                v0 = vv[0]; v1 = vv[1]; v2 = vv[2]; v3 = vv[3];
            }
            ushort4 qv = make_ushort4(f2bf(v0), f2bf(v1), f2bf(v2), f2bf(v3));
            int ldw = (b * STRIDE + e) >> 1;               // dword index, mult of 2
            int ph  = ldw ^ (((ldw >> 6) & 3) << 2);        // same swizzle as reads
            *(ushort4*)((char*)extl + (size_t)ph * 4) = qv;
        }
    }
    __syncthreads();

    const int lane = tid & 63;
    const int w    = tid >> 6;
    const int n    = lane & 31, kh = lane >> 5;
    const int brow = n & 7,  tb = n >> 3;
    // logical dword base for this lane's B-fragment stream (+8u per step)
    const int laneDW = brow * (STRIDE / 2) + 256 * w + 64 * tb + 4 * kh;

    // Groups balanced on padded-N + per-band overhead (sums 106-116)
    const int g_start[6] = {0, 2, 5, 8, 14, 20};
    const int g_list[20] = {0,5, 1,4,14, 2,3,6, 7,8,9,10,15,16, 11,12,13,17,18,19};

    for (int bi = g_start[grp]; bi < g_start[grp + 1]; ++bi) {
        const int band = g_list[bi];
        const int2 hh = hdr[band];
        const int k0 = hh.x, N = hh.y;
        const int Np   = (N + 7) & ~7;      // pad: extra steps have all-zero A rows
        const int umax = N + 5;             // clamp B stream (stays in staged span)
        const int bdw  = laneDW + (k0 >> 1);
        const short* ap = atab + (size_t)(band * MAXSTEP) * 512 + lane * 8;

        v16f ac0 = vzero(), ac1 = vzero(), ac2 = vzero(), ac3 = vzero();
        v8bf A0 = __builtin_bit_cast(v8bf, *(const v8s*)ap);
        v8bf A1 = __builtin_bit_cast(v8bf, *(const v8s*)(ap + 512));
        v8bf A2 = __builtin_bit_cast(v8bf, *(const v8s*)(ap + 1024));
        v8bf W[8];
        #pragma unroll
        for (int t = 0; t < 8; ++t) W[t] = ld_swz(extl, bdw + 8 * t);

        #define FSTEP(c) { \
            v8bf An = __builtin_bit_cast(v8bf, *(const v8s*)(ap + (size_t)(sb + (c) + 3) * 512)); \
            __builtin_amdgcn_s_setprio(1); \
            ac0 = __builtin_amdgcn_mfma_f32_32x32x16_bf16(A0, W[((c)+0)&7], ac0, 0, 0, 0); \
            ac1 = __builtin_amdgcn_mfma_f32_32x32x16_bf16(A0, W[((c)+2)&7], ac1, 0, 0, 0); \
            ac2 = __builtin_amdgcn_mfma_f32_32x32x16_bf16(A0, W[((c)+4)&7], ac2, 0, 0, 0); \
            ac3 = __builtin_amdgcn_mfma_f32_32x32x16_bf16(A0, W[((c)+6)&7], ac3, 0, 0, 0); \
            __builtin_amdgcn_s_setprio(0); \
            A0 = A1; A1 = A2; A2 = An; \
            int u = sb + (c) + 8; if (u > umax) u = umax; \
            W[(c) & 7] = ld_swz(extl, bdw + 8 * u); \
        }
        for (int sb = 0; sb < Np; sb += 8) {
            FSTEP(0) FSTEP(1) FSTEP(2) FSTEP(3)
            FSTEP(4) FSTEP(5) FSTEP(6) FSTEP(7)
        }
        #undef FSTEP

        // Epilogue: D row m = (reg&3) + 8*(reg>>2) + 4*kh; time = 512w + 128tb
        // + 32j + m. Plain stores (L2 merges; nontemporal was 2.1x ampl, r4).
        float* ob = out + ((size_t)(bg * 8 + brow) * NB + band) * LSEQ
                        + T0 + 512 * w + 128 * tb + 4 * kh;
        #pragma unroll
        for (int q = 0; q < 4; ++q) {
            *(float4*)(ob +      8 * q) = make_float4(ac0[4*q], ac0[4*q+1], ac0[4*q+2], ac0[4*q+3]);
            *(float4*)(ob + 32 + 8 * q) = make_float4(ac1[4*q], ac1[4*q+1], ac1[4*q+2], ac1[4*q+3]);
            *(float4*)(ob + 64 + 8 * q) = make_float4(ac2[4*q], ac2[4*q+1], ac2[4*q+2], ac2[4*q+3]);
            *(float4*)(ob + 96 + 8 * q) = make_float4(ac3[4*q], ac3[4*q+1], ac3[4*q+2], ac3[4*q+3]);
        }
    }
}

extern "C" void kernel_launch(void* const* d_in, const int* in_sizes, int n_in,
                              void* d_out, int out_size, void* d_ws, size_t ws_size,
                              hipStream_t stream) {
    const float* x  = (const float*)d_in[0];  // (128, 1, 16384) fp32
    const float* Kg = (const float*)d_in[1];  // (20, 513) fp32
    float* out = (float*)d_out;               // (128, 1, 20, 16384) fp32

    char* wsb = (char*)d_ws;
    int2*  hdr  = (int2*)(wsb + HDR_OFF);
    float* Cs   = (float*)(wsb + CS_OFF);
    short* atab = (short*)(wsb + ATAB_OFF);

    autoc_kernel<<<dim3(NB, 9), dim3(512), 0, stream>>>(Kg, Cs);
    table_kernel<<<dim3(NB), dim3(1024), 0, stream>>>(Cs, hdr, atab);
    filt_main<<<dim3(LSEQ / TT, 5, NBATCH / 8), dim3(256), 0, stream>>>(x, atab, hdr, out);
}

// Round 8
// 220.448 us; speedup vs baseline: 1.0230x; 1.0230x over previous
//
#include <hip/hip_runtime.h>

// Problem constants
#define LSEQ   16384
#define NB     20
#define NBATCH 128
#define TAPS   513
#define CT     (2*TAPS - 1)   // 1025 combined (autocorrelation) taps
#define MAXSTEP 80            // k-step table rows per band

// Main-kernel tiling: block = 4 batches x 4096 times, 4 waves.
// Wave: 4 batches x 1024 times; n = 8*b? no: n = b*8 + sub (4 batches x 8
// time-subtiles of 32); 4 accumulators at time offsets 256j. Stores are 1KB
// contiguous per (batch, j) -> fill-like write coalescing (the r4 nt-store
// 2.1x amplification proved the old batch-scattered stores hit memory as
// partial lines; fills prove coalesced pure-write does 6.7 TB/s).
#define TT     4096           // output times per block
#define NROW   4              // batch rows per block
#define SPANE  5136           // staged ext ushorts per row (max read 5119+16 pad)
#define STRIDE 5144           // row stride in ushorts; 2572 dwords = 12 mod 32
                              //  -> batch rows bank-staggered, B-reads uniform
#define EXTEND 16896          // 512 + LSEQ
#define GMAX   17407          // last valid ext index (LSEQ + 2*512 - 1)

// ws layout (bytes)
#define HDR_OFF  0            // int2 per band {k0, nsteps}: 160 B
#define CS_OFF   4096         // fp32 autocorr: 20 * CSTRIDE floats = 83.2 KB
#define CSTRIDE  1040         // floats per band row (1025 padded)
#define ATAB_OFF 98304        // bf16 A-fragment table: 20*80*64*16 B = 1.64 MB

typedef short  v8s  __attribute__((ext_vector_type(8)));
typedef __bf16 v8bf __attribute__((ext_vector_type(8)));
typedef float  v16f __attribute__((ext_vector_type(16)));

__device__ __forceinline__ unsigned short f2bf(float f) {  // RNE fp32->bf16
    union { float f; unsigned u; } v; v.f = f;
    return (unsigned short)((v.u + 0x7fffu + ((v.u >> 16) & 1u)) >> 16);
}

__device__ __forceinline__ v16f vzero() {
    v16f z;
    #pragma unroll
    for (int i = 0; i < 16; ++i) z[i] = 0.f;
    return z;
}

// ---- Autocorr kernel: grid (20 bands, 9 chunks of 128 d) x 512 threads ----
__global__ __launch_bounds__(512) void autoc_kernel(
    const float* __restrict__ Kg, float* __restrict__ Cs)
{
    __shared__ __align__(16) float kk4[4][520];
    __shared__ float ps[512];
    const int band = blockIdx.x, y = blockIdx.y;
    const int tid = threadIdx.x;
    const int rel = tid & 127, q = tid >> 7;
    const int d = 128 * y + rel;

    for (int j = tid; j < TAPS; j += 512) {
        float v = Kg[band * TAPS + j];
        kk4[0][j] = v;
        if (j >= 1) kk4[1][j - 1] = v;
        if (j >= 2) kk4[2][j - 2] = v;
        if (j >= 3) kk4[3][j - 3] = v;
    }
    if (tid < 40) {   // zero shifted-copy tails [TAPS-c, 520)
        int c = tid / 10, t = tid % 10;
        int j = 510 + t;
        if (j >= TAPS - c && j < 520) kk4[c][j] = 0.f;
    }
    __syncthreads();

    float s = 0.f;
    if (d < CT) {
        int al = d - 512; if (al < 0) al = -al;
        const int n  = TAPS - al;
        const int c  = al & 3, sh4 = (al >> 2) << 2;
        const int nq = (((n + 3) >> 2) + 3) & ~3;
        int i0 = q * nq, i1 = i0 + nq; if (i1 > n) i1 = n;
        float s0 = 0.f, s1 = 0.f, s2 = 0.f, s3 = 0.f;
        int i = i0;
        for (; i + 3 < i1; i += 4) {
            float4 a = *(const float4*)&kk4[0][i];
            float4 b = *(const float4*)&kk4[c][i + sh4];
            s0 = fmaf(a.x, b.x, s0);
            s1 = fmaf(a.y, b.y, s1);
            s2 = fmaf(a.z, b.z, s2);
            s3 = fmaf(a.w, b.w, s3);
        }
        for (; i < i1; ++i) s0 = fmaf(kk4[0][i], kk4[c][i + sh4], s0);
        s = (s0 + s1) + (s2 + s3);
    }
    ps[tid] = s;
    __syncthreads();
    if (q == 0 && d < CT) {
        float tot = (ps[rel] + ps[rel + 128]) + (ps[rel + 256] + ps[rel + 384]);
        Cs[band * CSTRIDE + d] = tot;
    }
}

// ---- Table kernel: one block per band; stage C in LDS, range-scan, emit ----
__global__ __launch_bounds__(1024) void table_kernel(
    const float* __restrict__ Cs, int2* __restrict__ hdr, short* __restrict__ atab)
{
    __shared__ float csh[CT];
    __shared__ int smin, smax, sk0, sN;
    const int band = blockIdx.x, tid = threadIdx.x;
    if (tid == 0) { smin = CT; smax = 0; }
    __syncthreads();

    const float* cb = Cs + band * CSTRIDE;
    int lmin = CT, lmax = 0;
    for (int j = tid; j < CT; j += 1024) {
        float v = cb[j];
        csh[j] = v;
        if (v != 0.f) { if (j < lmin) lmin = j; if (j > lmax) lmax = j; }
    }
    if (lmin < CT) atomicMin(&smin, lmin);
    if (lmax > 0)  atomicMax(&smax, lmax);
    __syncthreads();

    if (tid == 0) {
        int k0 = smin & ~15;
        int k1 = ((smax + 31) >> 4) << 4;
        int N  = (k1 - k0) / 16 + 1;              // <= 66
        int2 h; h.x = k0; h.y = N;
        hdr[band] = h;
        sk0 = k0; sN = N;
    }
    __syncthreads();

    const int k0 = sk0, N = sN;
    int nf = N + 3; if (nf > MAXSTEP) nf = MAXSTEP;  // rows 0..N+2 read by main
    for (int idx = tid; idx < nf * 64; idx += 1024) {
        int s = idx >> 6, lane = idx & 63;
        int m = lane & 31, kh = lane >> 5;
        int base = k0 + 16 * s + 8 * kh - m;
        v8s r;
        #pragma unroll
        for (int j = 0; j < 8; ++j) {
            int ci = base + j;
            float v = (ci >= 0 && ci < CT) ? csh[ci] : 0.f;
            r[j] = (short)f2bf(v);
        }
        *(v8s*)(atab + ((size_t)(band * MAXSTEP + s) * 64 + lane) * 8) = r;
    }
}

// ---- Main kernel ----
__global__ __launch_bounds__(256, 3) void filt_main(
    const float* __restrict__ x, const short* __restrict__ atab,
    const int2* __restrict__ hdr, float* __restrict__ out)
{
    __shared__ __align__(16) unsigned short extl[NROW * STRIDE];
    const int tid = threadIdx.x;
    const int tile = blockIdx.x, grp = blockIdx.y, bg = blockIdx.z;
    const int T0 = tile * TT;

    // ---- Stage odd-extended x as bf16 (4 batch rows, SPANE each) ----
    const bool edge = (T0 < 512) || (T0 + SPANE > EXTEND);
    for (int b = 0; b < NROW; ++b) {
        const float* xb = x + (size_t)(bg * NROW + b) * LSEQ;
        float x0 = 0.f, xN = 0.f;
        if (edge) { x0 = xb[0]; xN = xb[LSEQ - 1]; }
        for (int e4 = tid; e4 < SPANE / 4; e4 += 256) {
            const int e = 4 * e4;
            const int g0 = T0 + e;
            float v0, v1, v2, v3;
            if (g0 >= 512 && g0 + 4 <= EXTEND) {
                float4 xv = *(const float4*)(xb + (g0 - 512));
                v0 = xv.x; v1 = xv.y; v2 = xv.z; v3 = xv.w;
            } else {
                float vv[4];
                #pragma unroll
                for (int t = 0; t < 4; ++t) {
                    int g = g0 + t; if (g > GMAX) g = GMAX;  // pad; A rows are 0 there
                    vv[t] = (g < 512)    ? 2.f * x0 - xb[512 - g]
                          : (g < EXTEND) ? xb[g - 512]
                          :                2.f * xN - xb[2 * LSEQ + 512 - 2 - g];
                }
                v0 = vv[0]; v1 = vv[1]; v2 = vv[2]; v3 = vv[3];
            }
            ushort4 qv = make_ushort4(f2bf(v0), f2bf(v1), f2bf(v2), f2bf(v3));
            *(ushort4*)&extl[b * STRIDE + e] = qv;
        }
    }
    __syncthreads();

    const int lane = tid & 63;
    const int w    = tid >> 6;
    const int n    = lane & 31, kh = lane >> 5;
    const int b    = n >> 3, sub = n & 7;      // n = 8*b + sub
    // B-fragment ushort base: batch row + wave's 1024-time slice + 32*sub
    const unsigned short* bpb = extl + b * STRIDE + 1024 * w + 32 * sub + 8 * kh;

    // Groups balanced on N + per-band overhead
    const int g_start[6] = {0, 2, 5, 8, 14, 20};
    const int g_list[20] = {0,5, 1,4,14, 2,3,6, 7,8,9,10,15,16, 11,12,13,17,18,19};

    for (int bi = g_start[grp]; bi < g_start[grp + 1]; ++bi) {
        const int band = g_list[bi];
        const int2 hh = hdr[band];
        const int k0 = hh.x, N = hh.y;
        const unsigned short* bp = bpb + k0;
        const short* ap = atab + (size_t)(band * MAXSTEP) * 512 + lane * 8;

        v16f ac0 = vzero(), ac1 = vzero(), ac2 = vzero(), ac3 = vzero();
        // A prefetch depth 3
        v8bf A0 = __builtin_bit_cast(v8bf, *(const v8s*)ap);
        v8bf A1 = __builtin_bit_cast(v8bf, *(const v8s*)(ap + 512));
        v8bf A2 = __builtin_bit_cast(v8bf, *(const v8s*)(ap + 1024));

        #pragma unroll 2
        for (int s = 0; s < N; ++s) {
            v8bf An = __builtin_bit_cast(v8bf, *(const v8s*)(ap + (size_t)(s + 3) * 512));
            const unsigned short* bn = bp + 16 * s;
            v8bf B0 = *(const v8bf*)(bn);          // acc_j at time offset 256j
            v8bf B1 = *(const v8bf*)(bn + 256);
            v8bf B2 = *(const v8bf*)(bn + 512);
            v8bf B3 = *(const v8bf*)(bn + 768);
            __builtin_amdgcn_s_setprio(1);
            ac0 = __builtin_amdgcn_mfma_f32_32x32x16_bf16(A0, B0, ac0, 0, 0, 0);
            ac1 = __builtin_amdgcn_mfma_f32_32x32x16_bf16(A0, B1, ac1, 0, 0, 0);
            ac2 = __builtin_amdgcn_mfma_f32_32x32x16_bf16(A0, B2, ac2, 0, 0, 0);
            ac3 = __builtin_amdgcn_mfma_f32_32x32x16_bf16(A0, B3, ac3, 0, 0, 0);
            __builtin_amdgcn_s_setprio(0);
            A0 = A1; A1 = A2; A2 = An;
        }

        // Epilogue: D row m = (reg&3)+8*(reg>>2)+4*kh; time = 1024w + 256j +
        // 32*sub + m; batch = bg*4 + b. Per instruction: 8 subs x 128B = 1KB
        // contiguous runs per batch -> full-line L2 write combining.
        float* ob = out + ((size_t)(bg * NROW + b) * NB + band) * LSEQ
                        + T0 + 1024 * w + 32 * sub + 4 * kh;
        #pragma unroll
        for (int q = 0; q < 4; ++q) {
            *(float4*)(ob +       8 * q) = make_float4(ac0[4*q], ac0[4*q+1], ac0[4*q+2], ac0[4*q+3]);
            *(float4*)(ob + 256 + 8 * q) = make_float4(ac1[4*q], ac1[4*q+1], ac1[4*q+2], ac1[4*q+3]);
            *(float4*)(ob + 512 + 8 * q) = make_float4(ac2[4*q], ac2[4*q+1], ac2[4*q+2], ac2[4*q+3]);
            *(float4*)(ob + 768 + 8 * q) = make_float4(ac3[4*q], ac3[4*q+1], ac3[4*q+2], ac3[4*q+3]);
        }
    }
}

extern "C" void kernel_launch(void* const* d_in, const int* in_sizes, int n_in,
                              void* d_out, int out_size, void* d_ws, size_t ws_size,
                              hipStream_t stream) {
    const float* x  = (const float*)d_in[0];  // (128, 1, 16384) fp32
    const float* Kg = (const float*)d_in[1];  // (20, 513) fp32
    float* out = (float*)d_out;               // (128, 1, 20, 16384) fp32

    char* wsb = (char*)d_ws;
    int2*  hdr  = (int2*)(wsb + HDR_OFF);
    float* Cs   = (float*)(wsb + CS_OFF);
    short* atab = (short*)(wsb + ATAB_OFF);

    autoc_kernel<<<dim3(NB, 9), dim3(512), 0, stream>>>(Kg, Cs);
    table_kernel<<<dim3(NB), dim3(1024), 0, stream>>>(Cs, hdr, atab);
    filt_main<<<dim3(LSEQ / TT, 5, NBATCH / NROW), dim3(256), 0, stream>>>(x, atab, hdr, out);
}

// Round 9
// 205.755 us; speedup vs baseline: 1.0961x; 1.0714x over previous
//
#include <hip/hip_runtime.h>

// Problem constants
#define LSEQ   16384
#define NB     20
#define NBATCH 128
#define TAPS   513
#define CT     (2*TAPS - 1)   // 1025 combined (autocorrelation) taps
#define MAXSTEP 80            // k-step table rows per band

// Main-kernel tiling: block = 2 batches x 1024 times, 4 waves.
// Waves split BANDS (4 balanced groups), not time -> every block has
// identical weight; grid = 16 x 64 = 1024 uniform blocks = exactly 4/CU
// (no packing tail), LDS 8.3 KB -> 16 waves/CU (was 12 at 41 KB).
// Wave tile per band: m = fine time (32), n = 2 batches x 16 time-subtiles
// of 32; 2 accumulators at time offsets 0/512.
#define TT     1024           // output times per block
#define NROW   2              // batch rows per block
#define SPANE  2064           // staged ext ushorts per row (max read 2031 + pad)
#define STRIDE 2072           // row stride in ushorts; 1036 dw = 12 mod 32
#define EXTEND 16896          // 512 + LSEQ
#define GMAX   17407          // last valid ext index (LSEQ + 2*512 - 1)

// ws layout (bytes)
#define HDR_OFF  0            // int2 per band {k0, nsteps}: 160 B
#define CS_OFF   4096         // fp32 autocorr: 20 * CSTRIDE floats = 83.2 KB
#define CSTRIDE  1040         // floats per band row (1025 padded)
#define ATAB_OFF 98304        // bf16 A-fragment table: 20*80*64*16 B = 1.64 MB

typedef short  v8s  __attribute__((ext_vector_type(8)));
typedef __bf16 v8bf __attribute__((ext_vector_type(8)));
typedef float  v16f __attribute__((ext_vector_type(16)));

__device__ __forceinline__ unsigned short f2bf(float f) {  // RNE fp32->bf16
    union { float f; unsigned u; } v; v.f = f;
    return (unsigned short)((v.u + 0x7fffu + ((v.u >> 16) & 1u)) >> 16);
}

__device__ __forceinline__ v16f vzero() {
    v16f z;
    #pragma unroll
    for (int i = 0; i < 16; ++i) z[i] = 0.f;
    return z;
}

// ---- Autocorr kernel: grid (20 bands, 9 chunks of 128 d) x 512 threads ----
__global__ __launch_bounds__(512) void autoc_kernel(
    const float* __restrict__ Kg, float* __restrict__ Cs)
{
    __shared__ __align__(16) float kk4[4][520];
    __shared__ float ps[512];
    const int band = blockIdx.x, y = blockIdx.y;
    const int tid = threadIdx.x;
    const int rel = tid & 127, q = tid >> 7;
    const int d = 128 * y + rel;

    for (int j = tid; j < TAPS; j += 512) {
        float v = Kg[band * TAPS + j];
        kk4[0][j] = v;
        if (j >= 1) kk4[1][j - 1] = v;
        if (j >= 2) kk4[2][j - 2] = v;
        if (j >= 3) kk4[3][j - 3] = v;
    }
    if (tid < 40) {   // zero shifted-copy tails [TAPS-c, 520)
        int c = tid / 10, t = tid % 10;
        int j = 510 + t;
        if (j >= TAPS - c && j < 520) kk4[c][j] = 0.f;
    }
    __syncthreads();

    float s = 0.f;
    if (d < CT) {
        int al = d - 512; if (al < 0) al = -al;
        const int n  = TAPS - al;
        const int c  = al & 3, sh4 = (al >> 2) << 2;
        const int nq = (((n + 3) >> 2) + 3) & ~3;
        int i0 = q * nq, i1 = i0 + nq; if (i1 > n) i1 = n;
        float s0 = 0.f, s1 = 0.f, s2 = 0.f, s3 = 0.f;
        int i = i0;
        for (; i + 3 < i1; i += 4) {
            float4 a = *(const float4*)&kk4[0][i];
            float4 b = *(const float4*)&kk4[c][i + sh4];
            s0 = fmaf(a.x, b.x, s0);
            s1 = fmaf(a.y, b.y, s1);
            s2 = fmaf(a.z, b.z, s2);
            s3 = fmaf(a.w, b.w, s3);
        }
        for (; i < i1; ++i) s0 = fmaf(kk4[0][i], kk4[c][i + sh4], s0);
        s = (s0 + s1) + (s2 + s3);
    }
    ps[tid] = s;
    __syncthreads();
    if (q == 0 && d < CT) {
        float tot = (ps[rel] + ps[rel + 128]) + (ps[rel + 256] + ps[rel + 384]);
        Cs[band * CSTRIDE + d] = tot;
    }
}

// ---- Table kernel: one block per band; stage C in LDS, range-scan, emit ----
__global__ __launch_bounds__(1024) void table_kernel(
    const float* __restrict__ Cs, int2* __restrict__ hdr, short* __restrict__ atab)
{
    __shared__ float csh[CT];
    __shared__ int smin, smax, sk0, sN;
    const int band = blockIdx.x, tid = threadIdx.x;
    if (tid == 0) { smin = CT; smax = 0; }
    __syncthreads();

    const float* cb = Cs + band * CSTRIDE;
    int lmin = CT, lmax = 0;
    for (int j = tid; j < CT; j += 1024) {
        float v = cb[j];
        csh[j] = v;
        if (v != 0.f) { if (j < lmin) lmin = j; if (j > lmax) lmax = j; }
    }
    if (lmin < CT) atomicMin(&smin, lmin);
    if (lmax > 0)  atomicMax(&smax, lmax);
    __syncthreads();

    if (tid == 0) {
        int k0 = smin & ~15;
        int k1 = ((smax + 31) >> 4) << 4;
        int N  = (k1 - k0) / 16 + 1;              // <= 66
        int2 h; h.x = k0; h.y = N;
        hdr[band] = h;
        sk0 = k0; sN = N;
    }
    __syncthreads();

    const int k0 = sk0, N = sN;
    int nf = N + 3; if (nf > MAXSTEP) nf = MAXSTEP;  // rows 0..N+2 read by main
    for (int idx = tid; idx < nf * 64; idx += 1024) {
        int s = idx >> 6, lane = idx & 63;
        int m = lane & 31, kh = lane >> 5;
        int base = k0 + 16 * s + 8 * kh - m;
        v8s r;
        #pragma unroll
        for (int j = 0; j < 8; ++j) {
            int ci = base + j;
            float v = (ci >= 0 && ci < CT) ? csh[ci] : 0.f;
            r[j] = (short)f2bf(v);
        }
        *(v8s*)(atab + ((size_t)(band * MAXSTEP + s) * 64 + lane) * 8) = r;
    }
}

// ---- Main kernel ----
__global__ __launch_bounds__(256, 4) void filt_main(
    const float* __restrict__ x, const short* __restrict__ atab,
    const int2* __restrict__ hdr, float* __restrict__ out)
{
    __shared__ __align__(16) unsigned short extl[NROW * STRIDE];
    const int tid = threadIdx.x;
    const int tile = blockIdx.x, bg = blockIdx.y;
    const int T0 = tile * TT;

    // ---- Stage odd-extended x as bf16 (2 batch rows, SPANE each) ----
    const bool edge = (T0 < 512) || (T0 + SPANE > EXTEND);
    for (int b = 0; b < NROW; ++b) {
        const float* xb = x + (size_t)(bg * NROW + b) * LSEQ;
        float x0 = 0.f, xN = 0.f;
        if (edge) { x0 = xb[0]; xN = xb[LSEQ - 1]; }
        for (int e4 = tid; e4 < SPANE / 4; e4 += 256) {
            const int e = 4 * e4;
            const int g0 = T0 + e;
            float v0, v1, v2, v3;
            if (g0 >= 512 && g0 + 4 <= EXTEND) {
                float4 xv = *(const float4*)(xb + (g0 - 512));
                v0 = xv.x; v1 = xv.y; v2 = xv.z; v3 = xv.w;
            } else {
                float vv[4];
                #pragma unroll
                for (int t = 0; t < 4; ++t) {
                    int g = g0 + t; if (g > GMAX) g = GMAX;  // pad region, never read
                    vv[t] = (g < 512)    ? 2.f * x0 - xb[512 - g]
                          : (g < EXTEND) ? xb[g - 512]
                          :                2.f * xN - xb[2 * LSEQ + 512 - 2 - g];
                }
                v0 = vv[0]; v1 = vv[1]; v2 = vv[2]; v3 = vv[3];
            }
            ushort4 qv = make_ushort4(f2bf(v0), f2bf(v1), f2bf(v2), f2bf(v3));
            *(ushort4*)&extl[b * STRIDE + e] = qv;
        }
    }
    __syncthreads();

    const int lane = tid & 63;
    const int w    = tid >> 6;
    const int n    = lane & 31, kh = lane >> 5;
    const int b    = n >> 4, sub = n & 15;     // n = 16*b + sub
    const unsigned short* bpb = extl + b * STRIDE + 32 * sub + 8 * kh;

    // Per-WAVE band groups, balanced on N+3 (sums 99/99/96/102)
    const int gw_start[5] = {0, 3, 7, 11, 20};
    const int gw_list[20] = {0,7,8, 1,4,9,14, 2,3,5,12, 6,10,11,13,15,16,17,18,19};

    for (int bi = gw_start[w]; bi < gw_start[w + 1]; ++bi) {
        const int band = gw_list[bi];
        const int2 hh = hdr[band];
        const int k0 = hh.x, N = hh.y;
        const unsigned short* bp = bpb + k0;
        const short* ap = atab + (size_t)(band * MAXSTEP) * 512 + lane * 8;

        v16f ac0 = vzero(), ac1 = vzero();
        // A prefetch depth 3
        v8bf A0 = __builtin_bit_cast(v8bf, *(const v8s*)ap);
        v8bf A1 = __builtin_bit_cast(v8bf, *(const v8s*)(ap + 512));
        v8bf A2 = __builtin_bit_cast(v8bf, *(const v8s*)(ap + 1024));

        #pragma unroll 2
        for (int s = 0; s < N; ++s) {
            v8bf An = __builtin_bit_cast(v8bf, *(const v8s*)(ap + (size_t)(s + 3) * 512));
            const unsigned short* bn = bp + 16 * s;
            v8bf B0 = *(const v8bf*)(bn);          // acc_j at time offset 512j
            v8bf B1 = *(const v8bf*)(bn + 512);
            __builtin_amdgcn_s_setprio(1);
            ac0 = __builtin_amdgcn_mfma_f32_32x32x16_bf16(A0, B0, ac0, 0, 0, 0);
            ac1 = __builtin_amdgcn_mfma_f32_32x32x16_bf16(A0, B1, ac1, 0, 0, 0);
            __builtin_amdgcn_s_setprio(0);
            A0 = A1; A1 = A2; A2 = An;
        }

        // Epilogue: D row m = (reg&3)+8*(reg>>2)+4*kh; time = 512j + 32*sub + m.
        // Per store-instr: 16 subs x 128B = 2KB contiguous runs per batch.
        float* ob = out + ((size_t)(bg * NROW + b) * NB + band) * LSEQ
                        + T0 + 32 * sub + 4 * kh;
        #pragma unroll
        for (int q = 0; q < 4; ++q) {
            *(float4*)(ob +       8 * q) = make_float4(ac0[4*q], ac0[4*q+1], ac0[4*q+2], ac0[4*q+3]);
            *(float4*)(ob + 512 + 8 * q) = make_float4(ac1[4*q], ac1[4*q+1], ac1[4*q+2], ac1[4*q+3]);
        }
    }
}

extern "C" void kernel_launch(void* const* d_in, const int* in_sizes, int n_in,
                              void* d_out, int out_size, void* d_ws, size_t ws_size,
                              hipStream_t stream) {
    const float* x  = (const float*)d_in[0];  // (128, 1, 16384) fp32
    const float* Kg = (const float*)d_in[1];  // (20, 513) fp32
    float* out = (float*)d_out;               // (128, 1, 20, 16384) fp32

    char* wsb = (char*)d_ws;
    int2*  hdr  = (int2*)(wsb + HDR_OFF);
    float* Cs   = (float*)(wsb + CS_OFF);
    short* atab = (short*)(wsb + ATAB_OFF);

    autoc_kernel<<<dim3(NB, 9), dim3(512), 0, stream>>>(Kg, Cs);
    table_kernel<<<dim3(NB), dim3(1024), 0, stream>>>(Cs, hdr, atab);
    filt_main<<<dim3(LSEQ / TT, NBATCH / NROW), dim3(256), 0, stream>>>(x, atab, hdr, out);
}